// Round 1
// 549.641 us; speedup vs baseline: 1.0907x; 1.0907x over previous
//
#include <hip/hip_runtime.h>
#include <hip/hip_bf16.h>
#include <stdint.h>
#include <stddef.h>

#define IN_F   4096
#define OUT_F  4096
#define RANK   16
#define GROUP  128
#define M_TOT  8192   // 8 * 1024

// ---- GEMM geometry: 256x256 tile, BK=32, 8 waves, 3-deep counted-vmcnt pipe
#define BM     256
#define BN     256
#define BK     32
#define NIT    (IN_F / BK)        // 128 K-tiles
#define HALF_B 16384              // one A- or B-tile: 256*32*2B
#define TILE_B 32768              // A+B per K-tile
#define LDS_B  (3 * TILE_B)       // 96 KiB dynamic LDS

typedef __bf16 bf16_t;
typedef __bf16 bf16x4 __attribute__((ext_vector_type(4)));
typedef __bf16 bf16x8 __attribute__((ext_vector_type(8)));
typedef float  f32x4  __attribute__((ext_vector_type(4)));

// ---------------------------------------------------------------------------
// async global -> LDS, 16B per lane. LDS dest is wave-uniform base + lane*16.
// ---------------------------------------------------------------------------
__device__ static inline void load_lds16(const void* g, void* l) {
  __builtin_amdgcn_global_load_lds(
      (const __attribute__((address_space(1))) unsigned int*)g,
      (__attribute__((address_space(3))) unsigned int*)l,
      16, 0, 0);
}

// ---------------------------------------------------------------------------
// Kernel 1: w_q = fake-quant(w0 + lora_b @ lora_a), output bf16 [OUT_F][IN_F]
// (unchanged from previous round — ~20 us, memory-bound)
// ---------------------------------------------------------------------------
__global__ void __launch_bounds__(256)
quant_kernel(const float* __restrict__ w0, const float* __restrict__ la,
             const float* __restrict__ lb, const float* __restrict__ qs,
             bf16_t* __restrict__ wq)
{
  const int o = blockIdx.y;                            // output row
  const int i = blockIdx.x * 1024 + threadIdx.x * 4;   // column (x4)

  __shared__ float lbr[RANK];
  if (threadIdx.x < RANK) lbr[threadIdx.x] = lb[o * RANK + threadIdx.x];
  __syncthreads();

  const size_t off = (size_t)o * IN_F + i;
  const float4 w = *(const float4*)(w0 + off);
  float a0 = w.x, a1 = w.y, a2 = w.z, a3 = w.w;
  #pragma unroll
  for (int r = 0; r < RANK; ++r) {
    const float4 av = *(const float4*)(la + (size_t)r * IN_F + i);
    const float bv = lbr[r];
    a0 = fmaf(bv, av.x, a0);
    a1 = fmaf(bv, av.y, a1);
    a2 = fmaf(bv, av.z, a2);
    a3 = fmaf(bv, av.w, a3);
  }
  const float s   = qs[o * (IN_F / GROUP) + (i >> 7)];
  const float inv = 1.0f / (s + 1e-9f);
  const float q0 = rintf(fminf(fmaxf(a0 * inv, -8.0f), 7.0f)) * s;
  const float q1 = rintf(fminf(fmaxf(a1 * inv, -8.0f), 7.0f)) * s;
  const float q2 = rintf(fminf(fmaxf(a2 * inv, -8.0f), 7.0f)) * s;
  const float q3 = rintf(fminf(fmaxf(a3 * inv, -8.0f), 7.0f)) * s;
  bf16x4 v;
  v[0] = (bf16_t)q0; v[1] = (bf16_t)q1; v[2] = (bf16_t)q2; v[3] = (bf16_t)q3;
  *(bf16x4*)(wq + off) = v;
}

// ---------------------------------------------------------------------------
// Kernel 2: x fp32 -> bf16 (RNE), vectorized 8 elems/thread (unchanged)
// ---------------------------------------------------------------------------
__global__ void __launch_bounds__(256)
castx_kernel(const float* __restrict__ x, bf16_t* __restrict__ xb)
{
  const size_t i = ((size_t)blockIdx.x * 256 + threadIdx.x) * 8;
  const float4 a = *(const float4*)(x + i);
  const float4 b = *(const float4*)(x + i + 4);
  bf16x8 v;
  v[0] = (bf16_t)a.x; v[1] = (bf16_t)a.y; v[2] = (bf16_t)a.z; v[3] = (bf16_t)a.w;
  v[4] = (bf16_t)b.x; v[5] = (bf16_t)b.y; v[6] = (bf16_t)b.z; v[7] = (bf16_t)b.w;
  *(bf16x8*)(xb + i) = v;
}

// ---------------------------------------------------------------------------
// Kernel 3: GEMM  C[m][n] = sum_k A[m][k] * Bw[n][k] + bias[n]
//
// v4: 256x256 tile, 8 waves (2M x 4N), BK=32, 2 phases per K-tile.
// 3-deep K-tile circular LDS (96 KiB): compute tile t from buf t%3 while
// tile t+2 streams into buf (t+2)%3 via global_load_lds. Checkpoint at the
// end of each K-tile is s_waitcnt vmcnt(4): only tile t+2's 4 loads/thread
// remain in flight; tile t+1 is complete across all waves after the barrier.
// vmcnt NEVER drains to 0 in the main loop (T3+T4).
//
// LDS swizzle (T2): col16 ^= (row>>1)&3, applied BOTH on the pre-swizzled
// global staging source (global_load_lds writes linearly) and on the ds_read
// address. Each fixed 8-lane group then reads 8 distinct 16B bank slots.
//
// setprio(1) wraps each 16-MFMA cluster (T5); grid uses XCD swizzle (T1).
// ---------------------------------------------------------------------------
__global__ void __launch_bounds__(512, 2)
gemm_kernel(const bf16_t* __restrict__ A, const bf16_t* __restrict__ Bw,
            const float* __restrict__ bias, float* __restrict__ C)
{
  extern __shared__ __align__(16) char smem[];   // 3 * 32 KiB

  const int tid  = threadIdx.x;
  const int lane = tid & 63;
  const int lr   = lane & 15;    // frag row / C col
  const int quad = lane >> 4;    // 0..3
  const int wid  = tid >> 6;     // 0..7
  const int wm   = wid >> 2;     // 0..1  -> rows [wm*128, wm*128+128)
  const int wn   = wid & 3;      // 0..3  -> cols [wn*64,  wn*64+64)

  // XCD-aware bijective swizzle: 512 blocks, 8 XCDs, 64 blocks/XCD chunk.
  const int bid = blockIdx.x;
  const int swz = (bid & 7) * 64 + (bid >> 3);
  const int m0  = (swz >> 4) * BM;   // 32 m-blocks
  const int n0  = (swz & 15) * BN;   // 16 n-blocks

  // staging: chunk c = tid (rows 0..127) and tid+512 (rows 128..255) of a
  // [256][32] bf16 half; 4 chunks of 16B per 64B row. SOURCE column is
  // pre-swizzled so linear LDS + swizzled read round-trip correctly.
  const int srow = tid >> 2;                              // 0..127
  const int scol = ((tid & 3) ^ ((tid >> 3) & 3)) * 8;    // bf16 offset
  const bf16_t* gA0 = A  + (size_t)(m0 + srow) * IN_F + scol;
  const bf16_t* gA1 = gA0 + (size_t)128 * IN_F;
  const bf16_t* gB0 = Bw + (size_t)(n0 + srow) * IN_F + scol;
  const bf16_t* gB1 = gB0 + (size_t)128 * IN_F;

  // per-thread LDS read offsets (bytes) inside a 16 KiB half
  const int rswz = (quad ^ ((lr >> 1) & 3)) * 16;   // swizzled 16B slot
  const int aOff = (wm * 128 + lr) * 64 + rswz;
  const int bOff = (wn * 64  + lr) * 64 + rswz;

  f32x4 acc[8][4];
  #pragma unroll
  for (int i = 0; i < 8; ++i)
    #pragma unroll
    for (int j = 0; j < 4; ++j)
      acc[i][j] = (f32x4){0.f, 0.f, 0.f, 0.f};

  // ---- prologue: stage tiles 0 and 1; require tile 0 complete (vmcnt(4))
  {
    char* b0 = smem;
    char* b1 = smem + TILE_B;
    load_lds16(gA0,      b0 + tid * 16);
    load_lds16(gA1,      b0 + tid * 16 + 8192);
    load_lds16(gB0,      b0 + HALF_B + tid * 16);
    load_lds16(gB1,      b0 + HALF_B + tid * 16 + 8192);
    load_lds16(gA0 + BK, b1 + tid * 16);
    load_lds16(gA1 + BK, b1 + tid * 16 + 8192);
    load_lds16(gB0 + BK, b1 + HALF_B + tid * 16);
    load_lds16(gB1 + BK, b1 + HALF_B + tid * 16 + 8192);
    asm volatile("s_waitcnt vmcnt(4)" ::: "memory");
    __builtin_amdgcn_s_barrier();
  }

  int rb = 0, wb = 2;
  for (int t = 0; t < NIT; ++t) {
    const char* rA   = smem + rb * TILE_B;
    const char* rB   = rA + HALF_B;
    char*       wbuf = smem + wb * TILE_B;

    // ================= phase 0: quadrant fm 0..3 ==========================
    bf16x8 bfr[4];
    #pragma unroll
    for (int fn = 0; fn < 4; ++fn)
      bfr[fn] = *(const bf16x8*)(rB + bOff + fn * 1024);
    bf16x8 af[4];
    #pragma unroll
    for (int f = 0; f < 4; ++f)
      af[f] = *(const bf16x8*)(rA + aOff + f * 1024);

    if (t + 2 < NIT) {                       // stage A of tile t+2
      const size_t ko = (size_t)(t + 2) * BK;
      load_lds16(gA0 + ko, wbuf + tid * 16);
      load_lds16(gA1 + ko, wbuf + tid * 16 + 8192);
    }

    __builtin_amdgcn_s_barrier();
    asm volatile("s_waitcnt lgkmcnt(0)" ::: "memory");
    __builtin_amdgcn_sched_barrier(0);
    __builtin_amdgcn_s_setprio(1);
    #pragma unroll
    for (int fm = 0; fm < 4; ++fm)
      #pragma unroll
      for (int fn = 0; fn < 4; ++fn)
        acc[fm][fn] = __builtin_amdgcn_mfma_f32_16x16x32_bf16(
            af[fm], bfr[fn], acc[fm][fn], 0, 0, 0);
    __builtin_amdgcn_s_setprio(0);
    __builtin_amdgcn_s_barrier();

    // ================= phase 1: quadrant fm 4..7 ==========================
    #pragma unroll
    for (int f = 0; f < 4; ++f)
      af[f] = *(const bf16x8*)(rA + aOff + 4096 + f * 1024);

    if (t + 2 < NIT) {                       // stage B of tile t+2
      const size_t ko = (size_t)(t + 2) * BK;
      load_lds16(gB0 + ko, wbuf + HALF_B + tid * 16);
      load_lds16(gB1 + ko, wbuf + HALF_B + tid * 16 + 8192);
    }

    // K-tile checkpoint: tile t+1 must be complete; tile t+2 (newest 4
    // loads) may stay in flight. Tail iterations have no t+2 -> drain.
    if (t + 2 < NIT) asm volatile("s_waitcnt vmcnt(4)" ::: "memory");
    else             asm volatile("s_waitcnt vmcnt(0)" ::: "memory");
    __builtin_amdgcn_s_barrier();
    asm volatile("s_waitcnt lgkmcnt(0)" ::: "memory");
    __builtin_amdgcn_sched_barrier(0);
    __builtin_amdgcn_s_setprio(1);
    #pragma unroll
    for (int fm = 0; fm < 4; ++fm)
      #pragma unroll
      for (int fn = 0; fn < 4; ++fn)
        acc[4 + fm][fn] = __builtin_amdgcn_mfma_f32_16x16x32_bf16(
            af[fm], bfr[fn], acc[4 + fm][fn], 0, 0, 0);
    __builtin_amdgcn_s_setprio(0);
    __builtin_amdgcn_s_barrier();

    rb = rb + 1; if (rb == 3) rb = 0;
    wb = wb + 1; if (wb == 3) wb = 0;
  }

  // Epilogue: C/D layout col = lane&15, row = quad*4 + reg (m89-verified)
  #pragma unroll
  for (int fn = 0; fn < 4; ++fn) {
    const int gn = n0 + wn * 64 + fn * 16 + lr;
    const float bv = bias[gn];
    #pragma unroll
    for (int fm = 0; fm < 8; ++fm) {
      const int gm = m0 + wm * 128 + fm * 16 + quad * 4;
      #pragma unroll
      for (int r = 0; r < 4; ++r)
        C[(size_t)(gm + r) * OUT_F + gn] = acc[fm][fn][r] + bv;
    }
  }
}

// ---------------------------------------------------------------------------
extern "C" void kernel_launch(void* const* d_in, const int* in_sizes, int n_in,
                              void* d_out, int out_size, void* d_ws, size_t ws_size,
                              hipStream_t stream) {
  const float* x    = (const float*)d_in[0];  // [8,1024,4096]
  const float* w0   = (const float*)d_in[1];  // [4096,4096]
  const float* la   = (const float*)d_in[2];  // [16,4096]
  const float* lb   = (const float*)d_in[3];  // [4096,16]
  const float* qs   = (const float*)d_in[4];  // [131072]
  const float* bias = (const float*)d_in[5];  // [4096]
  float* out = (float*)d_out;                 // [8,1024,4096] fp32

  bf16_t* wq = (bf16_t*)d_ws;                                         // 32 MiB
  bf16_t* xb = (bf16_t*)((char*)d_ws + (size_t)OUT_F * IN_F * 2);     // 64 MiB

  static bool attr_done = false;
  if (!attr_done) {
    (void)hipFuncSetAttribute((const void*)gemm_kernel,
                              hipFuncAttributeMaxDynamicSharedMemorySize,
                              LDS_B);
    attr_done = true;
  }

  quant_kernel<<<dim3(IN_F / 1024, OUT_F), 256, 0, stream>>>(w0, la, lb, qs, wq);
  castx_kernel<<<(M_TOT * IN_F) / (256 * 8), 256, 0, stream>>>(x, xb);
  gemm_kernel<<<dim3((M_TOT / BM) * (OUT_F / BN)), 512, LDS_B, stream>>>(
      xb, wq, bias, out);
}

// Round 2
// 544.212 us; speedup vs baseline: 1.1016x; 1.0100x over previous
//
#include <hip/hip_runtime.h>
#include <hip/hip_bf16.h>
#include <stdint.h>
#include <stddef.h>

#define IN_F   4096
#define OUT_F  4096
#define RANK   16
#define GROUP  128
#define M_TOT  8192   // 8 * 1024

// ---- GEMM geometry: 256x256 tile, BK=32, 8 waves, 3-deep counted-vmcnt pipe
#define BM     256
#define BN     256
#define BK     32
#define NIT    (IN_F / BK)        // 128 K-tiles
#define HALF_B 16384              // one A- or B-tile: 256*32*2B
#define TILE_B 32768              // A+B per K-tile
#define LDS_B  (3 * TILE_B)       // 96 KiB dynamic LDS

typedef __bf16 bf16_t;
typedef __bf16 bf16x4 __attribute__((ext_vector_type(4)));
typedef __bf16 bf16x8 __attribute__((ext_vector_type(8)));
typedef float  f32x4  __attribute__((ext_vector_type(4)));

// ---------------------------------------------------------------------------
// async global -> LDS, 16B per lane. LDS dest is wave-uniform base + lane*16.
// ---------------------------------------------------------------------------
__device__ static inline void load_lds16(const void* g, void* l) {
  __builtin_amdgcn_global_load_lds(
      (const __attribute__((address_space(1))) unsigned int*)g,
      (__attribute__((address_space(3))) unsigned int*)l,
      16, 0, 0);
}

// ---------------------------------------------------------------------------
// Kernel 1: w_q = fake-quant(w0 + lora_b @ lora_a)  (unchanged, ~16 us, BW-bound)
// ---------------------------------------------------------------------------
__global__ void __launch_bounds__(256)
quant_kernel(const float* __restrict__ w0, const float* __restrict__ la,
             const float* __restrict__ lb, const float* __restrict__ qs,
             bf16_t* __restrict__ wq)
{
  const int o = blockIdx.y;                            // output row
  const int i = blockIdx.x * 1024 + threadIdx.x * 4;   // column (x4)

  __shared__ float lbr[RANK];
  if (threadIdx.x < RANK) lbr[threadIdx.x] = lb[o * RANK + threadIdx.x];
  __syncthreads();

  const size_t off = (size_t)o * IN_F + i;
  const float4 w = *(const float4*)(w0 + off);
  float a0 = w.x, a1 = w.y, a2 = w.z, a3 = w.w;
  #pragma unroll
  for (int r = 0; r < RANK; ++r) {
    const float4 av = *(const float4*)(la + (size_t)r * IN_F + i);
    const float bv = lbr[r];
    a0 = fmaf(bv, av.x, a0);
    a1 = fmaf(bv, av.y, a1);
    a2 = fmaf(bv, av.z, a2);
    a3 = fmaf(bv, av.w, a3);
  }
  const float s   = qs[o * (IN_F / GROUP) + (i >> 7)];
  const float inv = 1.0f / (s + 1e-9f);
  const float q0 = rintf(fminf(fmaxf(a0 * inv, -8.0f), 7.0f)) * s;
  const float q1 = rintf(fminf(fmaxf(a1 * inv, -8.0f), 7.0f)) * s;
  const float q2 = rintf(fminf(fmaxf(a2 * inv, -8.0f), 7.0f)) * s;
  const float q3 = rintf(fminf(fmaxf(a3 * inv, -8.0f), 7.0f)) * s;
  bf16x4 v;
  v[0] = (bf16_t)q0; v[1] = (bf16_t)q1; v[2] = (bf16_t)q2; v[3] = (bf16_t)q3;
  *(bf16x4*)(wq + off) = v;
}

// ---------------------------------------------------------------------------
// Kernel 2: x fp32 -> bf16 (RNE)  (unchanged, ~30 us, at BW floor)
// ---------------------------------------------------------------------------
__global__ void __launch_bounds__(256)
castx_kernel(const float* __restrict__ x, bf16_t* __restrict__ xb)
{
  const size_t i = ((size_t)blockIdx.x * 256 + threadIdx.x) * 8;
  const float4 a = *(const float4*)(x + i);
  const float4 b = *(const float4*)(x + i + 4);
  bf16x8 v;
  v[0] = (bf16_t)a.x; v[1] = (bf16_t)a.y; v[2] = (bf16_t)a.z; v[3] = (bf16_t)a.w;
  v[4] = (bf16_t)b.x; v[5] = (bf16_t)b.y; v[6] = (bf16_t)b.z; v[7] = (bf16_t)b.w;
  *(bf16x8*)(xb + i) = v;
}

// ---------------------------------------------------------------------------
// Kernel 3: GEMM  C[m][n] = sum_k A[m][k] * Bw[n][k] + bias[n]
//
// v5: register-pipelined fragments on top of v4's 3-deep counted-vmcnt LDS
// pipe. Each phase's ds_reads are issued ONE PHASE EARLY so LDS traffic for
// phase p+1 overlaps phase p's MFMA cluster (v4 serialized 770cy LDS burst +
// 620cy MFMA burst per phase -> measured 2500 cyc/K-tile; this targets
// max(LDS,MFMA) ~= 1390).
//
// Per K-tile T (2 phases, ONE barrier each):
//  even: barrier; gloadA(T+2); read afB(=A hi frags of T); SB(0);
//        MFMA fm0-3 on {afA,bfr_cur} read last phase
//  odd:  vmcnt(2) [publish T+1]; barrier; gloadB(T+2);
//        read bfr_nxt+afA(T+1); SB(0); MFMA fm4-7 on {afB,bfr_cur}
//
// Safety: (RAW) prefetch reads of tile T+1 sit after vmcnt(2)+barrier ->
// all waves' gloads for T+1 retired. (WAR) every wave's compiler-inserted
// lgkmcnt before an MFMA cluster covers all reads of tile T-1; that wait
// precedes the barrier after which tile T+2's gloads (same buffer) issue.
// bfr ping-pongs by K-tile parity (compile-time indexed); afA/afB are dead
// before their rewrite, so single-buffered.
// ---------------------------------------------------------------------------
__global__ void __launch_bounds__(512, 2)
gemm_kernel(const bf16_t* __restrict__ A, const bf16_t* __restrict__ Bw,
            const float* __restrict__ bias, float* __restrict__ C)
{
  extern __shared__ __align__(16) char smem[];   // 3 * 32 KiB

  const int tid  = threadIdx.x;
  const int lane = tid & 63;
  const int lr   = lane & 15;    // frag row / C col
  const int quad = lane >> 4;    // 0..3
  const int wid  = tid >> 6;     // 0..7
  const int wm   = wid >> 2;     // 0..1  -> rows [wm*128, wm*128+128)
  const int wn   = wid & 3;      // 0..3  -> cols [wn*64,  wn*64+64)

  // XCD-aware bijective swizzle: 512 blocks, 8 XCDs, 64 blocks/XCD chunk.
  const int bid = blockIdx.x;
  const int swz = (bid & 7) * 64 + (bid >> 3);
  const int m0  = (swz >> 4) * BM;   // 32 m-blocks
  const int n0  = (swz & 15) * BN;   // 16 n-blocks

  // staging: thread covers LDS bytes [tid*16, tid*16+16) of a [128][32] half
  // (+8192 for rows 128..255). SOURCE column pre-swizzled so linear LDS dest
  // + swizzled ds_read round-trip (global_load_lds writes linearly).
  const int srow = tid >> 2;                              // 0..127
  const int scol = ((tid & 3) ^ ((tid >> 3) & 3)) * 8;    // bf16 offset
  const bf16_t* gA0 = A  + (size_t)(m0 + srow) * IN_F + scol;
  const bf16_t* gA1 = gA0 + (size_t)128 * IN_F;
  const bf16_t* gB0 = Bw + (size_t)(n0 + srow) * IN_F + scol;
  const bf16_t* gB1 = gB0 + (size_t)128 * IN_F;

  // per-thread LDS read offsets (bytes) inside a 16 KiB half
  const int rswz = (quad ^ ((lr >> 1) & 3)) * 16;   // swizzled 16B slot
  const int aOff = (wm * 128 + lr) * 64 + rswz;
  const int bOff = (wn * 64  + lr) * 64 + rswz;

  f32x4 acc[8][4];
  #pragma unroll
  for (int i = 0; i < 8; ++i)
    #pragma unroll
    for (int j = 0; j < 4; ++j)
      acc[i][j] = (f32x4){0.f, 0.f, 0.f, 0.f};

  bf16x8 bfr0[4], bfr1[4], afA[4], afB[4];

  auto stageA = [&](int T, char* buf) {
    const size_t ko = (size_t)T * BK;
    load_lds16(gA0 + ko, buf + tid * 16);
    load_lds16(gA1 + ko, buf + tid * 16 + 8192);
  };
  auto stageB = [&](int T, char* buf) {
    const size_t ko = (size_t)T * BK;
    load_lds16(gB0 + ko, buf + HALF_B + tid * 16);
    load_lds16(gB1 + ko, buf + HALF_B + tid * 16 + 8192);
  };

  // even phase of K-tile T: prefetch afB(T); MFMA fm0-3 with {afA, bcur}
  auto ph_even = [&](int T, const char* rbuf, char* wbuf, bf16x8 (&bcur)[4]) {
    __builtin_amdgcn_s_barrier();
    __builtin_amdgcn_sched_barrier(0);
    if (T + 2 < NIT) stageA(T + 2, wbuf);
    #pragma unroll
    for (int f = 0; f < 4; ++f)
      afB[f] = *(const bf16x8*)(rbuf + aOff + 4096 + f * 1024);
    __builtin_amdgcn_sched_barrier(0);
    __builtin_amdgcn_s_setprio(1);
    #pragma unroll
    for (int fm = 0; fm < 4; ++fm)
      #pragma unroll
      for (int fn = 0; fn < 4; ++fn)
        acc[fm][fn] = __builtin_amdgcn_mfma_f32_16x16x32_bf16(
            afA[fm], bcur[fn], acc[fm][fn], 0, 0, 0);
    __builtin_amdgcn_s_setprio(0);
  };

  // odd phase of K-tile T: publish T+1; prefetch bnxt+afA(T+1);
  // MFMA fm4-7 with {afB, bcur}
  auto ph_odd = [&](int T, const char* rnext, char* wbuf,
                    bf16x8 (&bcur)[4], bf16x8 (&bnxt)[4]) {
    if (T + 2 < NIT) asm volatile("s_waitcnt vmcnt(2)" ::: "memory");
    else             asm volatile("s_waitcnt vmcnt(0)" ::: "memory");
    __builtin_amdgcn_s_barrier();
    __builtin_amdgcn_sched_barrier(0);
    if (T + 2 < NIT) stageB(T + 2, wbuf);
    if (T + 1 < NIT) {
      #pragma unroll
      for (int f = 0; f < 4; ++f)
        bnxt[f] = *(const bf16x8*)(rnext + HALF_B + bOff + f * 1024);
      #pragma unroll
      for (int f = 0; f < 4; ++f)
        afA[f] = *(const bf16x8*)(rnext + aOff + f * 1024);
    }
    __builtin_amdgcn_sched_barrier(0);
    __builtin_amdgcn_s_setprio(1);
    #pragma unroll
    for (int fm = 0; fm < 4; ++fm)
      #pragma unroll
      for (int fn = 0; fn < 4; ++fn)
        acc[4 + fm][fn] = __builtin_amdgcn_mfma_f32_16x16x32_bf16(
            afB[fm], bcur[fn], acc[4 + fm][fn], 0, 0, 0);
    __builtin_amdgcn_s_setprio(0);
  };

  // ---- prologue: stage tiles 0,1; publish tile 0; prefetch bfr0+afA(tile 0)
  {
    stageA(0, smem);          stageB(0, smem);
    stageA(1, smem + TILE_B); stageB(1, smem + TILE_B);
    asm volatile("s_waitcnt vmcnt(4)" ::: "memory");
    __builtin_amdgcn_s_barrier();
    __builtin_amdgcn_sched_barrier(0);
    #pragma unroll
    for (int f = 0; f < 4; ++f)
      bfr0[f] = *(const bf16x8*)(smem + HALF_B + bOff + f * 1024);
    #pragma unroll
    for (int f = 0; f < 4; ++f)
      afA[f] = *(const bf16x8*)(smem + aOff + f * 1024);
  }

  int rb = 0;
  for (int tt = 0; tt < NIT; tt += 2) {
    const int rb1 = (rb + 1 == 3) ? 0 : rb + 1;
    const int rb2 = (rb1 + 1 == 3) ? 0 : rb1 + 1;
    char* b_rb  = smem + rb  * TILE_B;
    char* b_rb1 = smem + rb1 * TILE_B;
    char* b_rb2 = smem + rb2 * TILE_B;

    // K-tile tt   : read b_rb,  write tile tt+2 -> b_rb2, bfr parity 0
    ph_even(tt,     b_rb,  b_rb2, bfr0);
    ph_odd (tt,     b_rb1, b_rb2, bfr0, bfr1);
    // K-tile tt+1 : read b_rb1, write tile tt+3 -> b_rb,  bfr parity 1
    ph_even(tt + 1, b_rb1, b_rb,  bfr1);
    ph_odd (tt + 1, b_rb2, b_rb,  bfr1, bfr0);

    rb = rb2;
  }

  // Epilogue: C/D layout col = lane&15, row = quad*4 + reg (m89-verified)
  #pragma unroll
  for (int fn = 0; fn < 4; ++fn) {
    const int gn = n0 + wn * 64 + fn * 16 + lr;
    const float bv = bias[gn];
    #pragma unroll
    for (int fm = 0; fm < 8; ++fm) {
      const int gm = m0 + wm * 128 + fm * 16 + quad * 4;
      #pragma unroll
      for (int r = 0; r < 4; ++r)
        C[(size_t)(gm + r) * OUT_F + gn] = acc[fm][fn][r] + bv;
    }
  }
}

// ---------------------------------------------------------------------------
extern "C" void kernel_launch(void* const* d_in, const int* in_sizes, int n_in,
                              void* d_out, int out_size, void* d_ws, size_t ws_size,
                              hipStream_t stream) {
  const float* x    = (const float*)d_in[0];  // [8,1024,4096]
  const float* w0   = (const float*)d_in[1];  // [4096,4096]
  const float* la   = (const float*)d_in[2];  // [16,4096]
  const float* lb   = (const float*)d_in[3];  // [4096,16]
  const float* qs   = (const float*)d_in[4];  // [131072]
  const float* bias = (const float*)d_in[5];  // [4096]
  float* out = (float*)d_out;                 // [8,1024,4096] fp32

  bf16_t* wq = (bf16_t*)d_ws;                                         // 32 MiB
  bf16_t* xb = (bf16_t*)((char*)d_ws + (size_t)OUT_F * IN_F * 2);     // 64 MiB

  static bool attr_done = false;
  if (!attr_done) {
    (void)hipFuncSetAttribute((const void*)gemm_kernel,
                              hipFuncAttributeMaxDynamicSharedMemorySize,
                              LDS_B);
    attr_done = true;
  }

  quant_kernel<<<dim3(IN_F / 1024, OUT_F), 256, 0, stream>>>(w0, la, lb, qs, wq);
  castx_kernel<<<(M_TOT * IN_F) / (256 * 8), 256, 0, stream>>>(x, xb);
  gemm_kernel<<<dim3((M_TOT / BM) * (OUT_F / BN)), 512, LDS_B, stream>>>(
      xb, wq, bias, out);
}